// Round 16
// baseline (243.411 us; speedup 1.0000x reference)
//
#include <hip/hip_runtime.h>

// MultiHeadAttention: BS=4, N=2048, D=512, H=8, DK=64. fp32 in/out, bf16 MFMA compute.
// Round 21: two attn-only tweaks on the R20 anchor (dbuf, 1 barrier/tile, 61us):
// (1) T5 s_setprio(1) around MFMA clusters (8 waves/CU with phase diversity ->
//     scheduler can favor MFMA-issuing waves; +4-7% measured on attn in learn_hip);
// (2) XCD-aware grid: flatten to 1D, lin = h + 8*(b*16 + qtile) -> all 16 q-blocks
//     of head h land on XCD h (round-robin dispatch), K/V per XCD = 2MB < 4MB L2.
// GEMMs (R11 64x64) and cvt_all frozen to isolate the change.

#define BS_    4
#define NSEQ   2048
#define DMODEL 512
#define NH     8
#define DKH    64
#define MROWS  (BS_ * NSEQ)   // 8192
#define NW32   (NSEQ / 32)    // 64 mask words per row
#define NWORDS (BS_ * NSEQ * NSEQ / 32)  // 524288 packed mask words

typedef unsigned short ushort_t;
typedef __attribute__((ext_vector_type(8))) short short8;   // 8 bf16 (4 VGPRs)
typedef __attribute__((ext_vector_type(4))) float floatx4;  // 4 fp32 acc

__device__ __forceinline__ ushort_t f2bf(float f) {
    unsigned int x = __builtin_bit_cast(unsigned int, f);
    unsigned int lsb = (x >> 16) & 1u;
    x += 0x7fffu + lsb;          // round-to-nearest-even
    return (ushort_t)(x >> 16);
}
__device__ __forceinline__ floatx4 mfma_bf16(short8 a, short8 b, floatx4 c) {
    return __builtin_amdgcn_mfma_f32_16x16x32_bf16(a, b, c, 0, 0, 0);
}
__device__ __forceinline__ void gld16(const ushort_t* g, ushort_t* l) {
    __builtin_amdgcn_global_load_lds(
        (const __attribute__((address_space(1))) unsigned int*)g,
        (__attribute__((address_space(3))) unsigned int*)l, 16, 0, 0);
}
__device__ __forceinline__ unsigned int cvt_pk_bf16(float lo, float hi) {
    unsigned int r;
    asm("v_cvt_pk_bf16_f32 %0, %1, %2" : "=v"(r) : "v"(lo), "v"(hi));
    return r;
}
__device__ __forceinline__ float fexp2(float x) {
#if __has_builtin(__builtin_amdgcn_exp2f)
    return __builtin_amdgcn_exp2f(x);   // raw v_exp_f32
#else
    return exp2f(x);
#endif
}
// gfx950: swap a[32:63] <-> b[0:31]
__device__ __forceinline__ void permlane32_swap(unsigned& a, unsigned& b) {
    asm volatile("v_permlane32_swap_b32 %0, %1" : "+v"(a), "+v"(b));
}
// gfx950: swap a[16:31]<->b[0:15] and a[48:63]<->b[32:47]
__device__ __forceinline__ void permlane16_swap(unsigned& a, unsigned& b) {
    asm volatile("v_permlane16_swap_b32 %0, %1" : "+v"(a), "+v"(b));
}
// spread 8 bits of b to positions 0,4,8,...,28
__device__ __forceinline__ unsigned spread4(unsigned b) {
    b = (b | (b << 12)) & 0x000F000Fu;
    b = (b | (b << 6))  & 0x03030303u;
    b = (b | (b << 3))  & 0x11111111u;
    return b;
}

// ---------------- fp32 -> bf16 converts + weights + att_mas bit-pack ----------------
// grid (4096, 8): y=0..2 QKV slices; y=3 weights; y=4..7 mask quarters (coalesced
// float4/thread + 4 ballots; lanes 0..7 of each wave emit the 8 packed words).
__global__ __launch_bounds__(256) void cvt_all(const float* __restrict__ a,
                                               const float* __restrict__ b,
                                               const float* __restrict__ c,
                                               const float* __restrict__ wq,
                                               const float* __restrict__ wk,
                                               const float* __restrict__ wv,
                                               const float* __restrict__ wo,
                                               const float* __restrict__ am,
                                               ushort_t* __restrict__ dst,
                                               ushort_t* __restrict__ wdst,
                                               unsigned int* __restrict__ mb, int n4) {
    const int i = blockIdx.x * blockDim.x + threadIdx.x;
    const int yy = blockIdx.y;
    if (yy >= 4) {
        // g indexes float4s of att_mas; elements 4g..4g+3; word w = elems 32w..32w+31
        const int g = ((yy - 4) * 4096 + blockIdx.x) * 256 + threadIdx.x;
        const float4 v = ((const float4*)am)[g];
        const unsigned long long b0 = __ballot(v.x != 0.f);
        const unsigned long long b1 = __ballot(v.y != 0.f);
        const unsigned long long b2 = __ballot(v.z != 0.f);
        const unsigned long long b3 = __ballot(v.w != 0.f);
        const int l = threadIdx.x & 63;
        if (l < 8) {
            const unsigned B0 = (unsigned)((b0 >> (8 * l)) & 0xFFull);
            const unsigned B1 = (unsigned)((b1 >> (8 * l)) & 0xFFull);
            const unsigned B2 = (unsigned)((b2 >> (8 * l)) & 0xFFull);
            const unsigned B3 = (unsigned)((b3 >> (8 * l)) & 0xFFull);
            const unsigned w = spread4(B0) | (spread4(B1) << 1) |
                               (spread4(B2) << 2) | (spread4(B3) << 3);
            const int g0 = g & ~63;           // wave-base float4 index
            mb[(g0 >> 3) + l] = w;
        }
        return;
    }
    if (yy == 3) {
        const int wn4 = DMODEL * DMODEL / 4;          // 65536 float4 per weight
        if (i < 4 * wn4) {
            const int w = i >> 16;
            const float* src = (w == 0) ? wq : (w == 1) ? wk : (w == 2) ? wv : wo;
            const float4 v = ((const float4*)src)[i & (wn4 - 1)];
            ushort4 o;
            o.x = f2bf(v.x); o.y = f2bf(v.y); o.z = f2bf(v.z); o.w = f2bf(v.w);
            ((ushort4*)wdst)[i] = o;
        }
        return;
    }
    const float* src = (yy == 0) ? a : (yy == 1) ? b : c;
    ushort_t* d = dst + (size_t)yy * ((size_t)n4 * 4);
    const float4 v = ((const float4*)src)[i];
    ushort4 o;
    o.x = f2bf(v.x); o.y = f2bf(v.y); o.z = f2bf(v.z); o.w = f2bf(v.w);
    ((ushort4*)d)[i] = o;
}

// ---------------- fused projection GEMM (Q/K/V via blockIdx.z), 64x64 tile, BK=64 ----------------
__global__ __launch_bounds__(256) void gemm_proj(const ushort_t* __restrict__ Xall,
                                                 const ushort_t* __restrict__ Wall,
                                                 const float* __restrict__ qmas,
                                                 const float* __restrict__ kmas,
                                                 ushort_t* __restrict__ Qh,
                                                 ushort_t* __restrict__ Kh,
                                                 ushort_t* __restrict__ Vt) {
    __shared__ ushort_t As[64 * 64];   // 8 KB
    __shared__ ushort_t Bs[64 * 64];   // 8 KB
    const int z = blockIdx.z;
    const ushort_t* X  = Xall + (size_t)z * MROWS * DMODEL;
    const ushort_t* Wb = Wall + (size_t)z * DMODEL * DMODEL;
    const float* rowmask = (z == 0) ? qmas : kmas;

    const int tid  = threadIdx.x;
    const int wave = tid >> 6;
    const int lane = tid & 63;
    const int l16  = lane & 15;
    const int quad = lane >> 4;
    const int wr   = wave >> 1;
    const int wc   = wave & 1;
    const int m0   = blockIdx.x * 64;
    const int n0   = blockIdx.y * 64;

    floatx4 acc[2][2];
#pragma unroll
    for (int t = 0; t < 2; ++t)
#pragma unroll
        for (int u = 0; u < 2; ++u) acc[t][u] = (floatx4){0.f, 0.f, 0.f, 0.f};

    for (int k0 = 0; k0 < DMODEL; k0 += 64) {
#pragma unroll
        for (int i = 0; i < 2; ++i) {
            const int cch = tid + i * 256;               // 16B chunk id, 0..511
            const int row = cch >> 3;
            const int sc  = 8 * ((cch & 7) ^ (row & 7)); // pre-swizzled source col
            gld16(X  + (size_t)(m0 + row) * DMODEL + k0 + sc, &As[cch * 8]);
            gld16(Wb + (size_t)(n0 + row) * DMODEL + k0 + sc, &Bs[cch * 8]);
        }
        __syncthreads();
#pragma unroll
        for (int kk = 0; kk < 64; kk += 32) {
            const int pc = (((kk >> 3) | quad) ^ (l16 & 7)) * 8;
            short8 a[2], b[2];
#pragma unroll
            for (int t = 0; t < 2; ++t)
                a[t] = *(const short8*)&As[(wr * 32 + t * 16 + l16) * 64 + pc];
#pragma unroll
            for (int u = 0; u < 2; ++u)
                b[u] = *(const short8*)&Bs[(wc * 32 + u * 16 + l16) * 64 + pc];
#pragma unroll
            for (int t = 0; t < 2; ++t)
#pragma unroll
                for (int u = 0; u < 2; ++u) acc[t][u] = mfma_bf16(a[t], b[u], acc[t][u]);
        }
        __syncthreads();
    }

    float rm[2][4];
#pragma unroll
    for (int t = 0; t < 2; ++t)
#pragma unroll
        for (int r = 0; r < 4; ++r)
            rm[t][r] = rowmask[m0 + wr * 32 + t * 16 + quad * 4 + r];
    if (z == 0) {
        // fold log2(e)/sqrt(dk) into Qh so attn uses exp2(S) directly
#pragma unroll
        for (int t = 0; t < 2; ++t)
#pragma unroll
            for (int r = 0; r < 4; ++r) rm[t][r] *= 0.18033688011112042f;
    }

    const int bb    = m0 >> 11;
    const int nbase = (m0 & (NSEQ - 1)) + wr * 32;
#pragma unroll
    for (int t = 0; t < 2; ++t) {
#pragma unroll
        for (int u = 0; u < 2; ++u) {
            const int d = n0 + wc * 32 + u * 16 + l16;
            const int h = d >> 6, cc = d & 63;
            if (z < 2) {
                ushort_t* dst = (z == 0) ? Qh : Kh;
#pragma unroll
                for (int r = 0; r < 4; ++r) {
                    const int n = nbase + t * 16 + quad * 4 + r;
                    dst[((size_t)(bb * NH + h) * NSEQ + n) * DKH + cc] =
                        f2bf(acc[t][u][r] * rm[t][r]);
                }
            } else {
                ushort4 pk;
                pk.x = f2bf(acc[t][u][0] * rm[t][0]);
                pk.y = f2bf(acc[t][u][1] * rm[t][1]);
                pk.z = f2bf(acc[t][u][2] * rm[t][2]);
                pk.w = f2bf(acc[t][u][3] * rm[t][3]);
                const int n = nbase + t * 16 + quad * 4;
                *(ushort4*)(Vt + ((size_t)(bb * NH + h) * DKH + cc) * NSEQ + n) = pk;
            }
        }
    }
}

// ---------------- output GEMM, 64x64 tile, BK=64, swizzled ----------------
__global__ __launch_bounds__(256) void gemm_out(const ushort_t* __restrict__ X,
                                                const ushort_t* __restrict__ Wb,
                                                const float* __restrict__ rowmask,
                                                float* __restrict__ dst) {
    __shared__ ushort_t As[64 * 64];
    __shared__ ushort_t Bs[64 * 64];
    const int tid  = threadIdx.x;
    const int wave = tid >> 6;
    const int lane = tid & 63;
    const int l16  = lane & 15;
    const int quad = lane >> 4;
    const int wr   = wave >> 1;
    const int wc   = wave & 1;
    const int m0   = blockIdx.x * 64;
    const int n0   = blockIdx.y * 64;

    floatx4 acc[2][2];
#pragma unroll
    for (int t = 0; t < 2; ++t)
#pragma unroll
        for (int u = 0; u < 2; ++u) acc[t][u] = (floatx4){0.f, 0.f, 0.f, 0.f};

    for (int k0 = 0; k0 < DMODEL; k0 += 64) {
#pragma unroll
        for (int i = 0; i < 2; ++i) {
            const int cch = tid + i * 256;
            const int row = cch >> 3;
            const int sc  = 8 * ((cch & 7) ^ (row & 7));
            gld16(X  + (size_t)(m0 + row) * DMODEL + k0 + sc, &As[cch * 8]);
            gld16(Wb + (size_t)(n0 + row) * DMODEL + k0 + sc, &Bs[cch * 8]);
        }
        __syncthreads();
#pragma unroll
        for (int kk = 0; kk < 64; kk += 32) {
            const int pc = (((kk >> 3) | quad) ^ (l16 & 7)) * 8;
            short8 a[2], b[2];
#pragma unroll
            for (int t = 0; t < 2; ++t)
                a[t] = *(const short8*)&As[(wr * 32 + t * 16 + l16) * 64 + pc];
#pragma unroll
            for (int u = 0; u < 2; ++u)
                b[u] = *(const short8*)&Bs[(wc * 32 + u * 16 + l16) * 64 + pc];
#pragma unroll
            for (int t = 0; t < 2; ++t)
#pragma unroll
                for (int u = 0; u < 2; ++u) acc[t][u] = mfma_bf16(a[t], b[u], acc[t][u]);
        }
        __syncthreads();
    }

#pragma unroll
    for (int t = 0; t < 2; ++t) {
#pragma unroll
        for (int r = 0; r < 4; ++r) {
            const int m = m0 + wr * 32 + t * 16 + quad * 4 + r;
            const float rm = rowmask[m];
#pragma unroll
            for (int u = 0; u < 2; ++u) {
                const int d = n0 + wc * 32 + u * 16 + l16;
                dst[(size_t)m * DMODEL + d] = acc[t][u][r] * rm;
            }
        }
    }
}

// ---------------- flash attention: 1D XCD-swizzled grid, dbuf LDS, setprio MFMA ----------------
// grid = 512 blocks 1D: lin = h + 8*(b*16 + qtile) -> all 16 q-blocks of head h on
// XCD h (round-robin dispatch); per-XCD K/V working set 2MB < 4MB L2.
// Structure otherwise = R20: K+V dbuf, 1 barrier/tile, in-register P (permlane),
// l via mfma(P, ones), next-tile gather issued after the barrier.
__global__ __launch_bounds__(256, 2) void attn_kernel(const ushort_t* __restrict__ Qh,
                                                      const ushort_t* __restrict__ Kh,
                                                      const ushort_t* __restrict__ Vt,
                                                      const unsigned int* __restrict__ Mb,
                                                      const float* __restrict__ kmas,
                                                      ushort_t* __restrict__ y) {
    __shared__ __align__(16) ushort_t Ks[2][128 * 72];   // 36864 B
    __shared__ __align__(16) ushort_t Vs[2][64 * 136];   // 34816 B (total 71680)

    const int tid  = threadIdx.x;
    const int lane = tid & 63;
    const int wave = tid >> 6;
    const int l16  = lane & 15;
    const int quad = lane >> 4;
    // XCD-aware decode: lin = h + 8*(b*16 + qtile)
    const int lin   = blockIdx.x;
    const int h     = lin & 7;
    const int rest  = lin >> 3;          // b*16 + qtile
    const int b     = rest >> 4;
    const int qtile = rest & 15;
    const int qw    = qtile * 128 + wave * 32;   // this wave's 32 q-rows

    const ushort_t* Kb = Kh + (size_t)(b * NH + h) * NSEQ * DKH;
    const ushort_t* Vb = Vt + (size_t)(b * NH + h) * DKH * NSEQ;
    // per-lane mask rows: q = qw + l16 (group 0) and qw + 16 + l16 (group 1)
    const uint4* Mv0 = (const uint4*)(Mb + ((size_t)(b * NSEQ + qw) + l16) * NW32);
    const uint4* Mv1 = (const uint4*)(Mb + ((size_t)(b * NSEQ + qw) + 16 + l16) * NW32);

    const ushort_t* Qp0 = Qh + ((size_t)((b * NH + h) * NSEQ) + qw + l16) * DKH + quad * 8;
    const ushort_t* Qp1 = Qp0 + 16 * DKH;
    const short8 qf0a = *(const short8*)Qp0;
    const short8 qf0b = *(const short8*)(Qp0 + 32);
    const short8 qf1a = *(const short8*)Qp1;
    const short8 qf1b = *(const short8*)(Qp1 + 32);

    // all-ones bf16 B-operand for row-sum MFMA (bf16 1.0 = 0x3F80)
    const short8 ones = {(short)0x3F80, (short)0x3F80, (short)0x3F80, (short)0x3F80,
                         (short)0x3F80, (short)0x3F80, (short)0x3F80, (short)0x3F80};

    floatx4 accA[4], accB[4];
    floatx4 accL0 = (floatx4){0.f, 0.f, 0.f, 0.f};   // row-sums l, group 0
    floatx4 accL1 = (floatx4){0.f, 0.f, 0.f, 0.f};   // row-sums l, group 1
#pragma unroll
    for (int ct = 0; ct < 4; ++ct) {
        accA[ct] = (floatx4){0.f, 0.f, 0.f, 0.f};
        accB[ct] = (floatx4){0.f, 0.f, 0.f, 0.f};
    }

// S fragment FR (compile-time after unroll) -> packed P words for both groups
#define SFRAG(FR, PX0, PY0, PX1, PY1) do {                                          \
    const short8 ka = *(const short8*)&Ksb[((FR) * 16 + l16) * 72 + quad * 8];      \
    const short8 kb = *(const short8*)&Ksb[((FR) * 16 + l16) * 72 + 32 + quad * 8]; \
    __builtin_amdgcn_s_setprio(1);                                                  \
    floatx4 s0 = {0.f, 0.f, 0.f, 0.f};                                              \
    s0 = mfma_bf16(ka, qf0a, s0);                                                   \
    s0 = mfma_bf16(kb, qf0b, s0);                                                   \
    floatx4 s1 = {0.f, 0.f, 0.f, 0.f};                                              \
    s1 = mfma_bf16(ka, qf1a, s1);                                                   \
    s1 = mfma_bf16(kb, qf1b, s1);                                                   \
    __builtin_amdgcn_s_setprio(0);                                                  \
    float p0[4], p1[4];                                                             \
    _Pragma("unroll")                                                               \
    for (int r = 0; r < 4; ++r) {                                                   \
        const int bitp = (((FR) & 1) << 4) + r;                                     \
        const unsigned m0m =                                                        \
            (unsigned)__builtin_amdgcn_sbfe((int)wsh0[(FR) >> 1], bitp, 1);         \
        const unsigned m1m =                                                        \
            (unsigned)__builtin_amdgcn_sbfe((int)wsh1[(FR) >> 1], bitp, 1);         \
        p0[r] = __builtin_bit_cast(float,                                           \
                    __builtin_bit_cast(unsigned, fexp2(s0[r])) & m0m);              \
        p1[r] = __builtin_bit_cast(float,                                           \
                    __builtin_bit_cast(unsigned, fexp2(s1[r])) & m1m);              \
    }                                                                               \
    PX0 = cvt_pk_bf16(p0[0], p0[1]); PY0 = cvt_pk_bf16(p0[2], p0[3]);               \
    PX1 = cvt_pk_bf16(p1[0], p1[1]); PY1 = cvt_pk_bf16(p1[2], p1[3]);               \
} while (0)

    // ---- prologue: gather tile 0 ----
    short8 kv[4], vv[4];
    uint4 mw0n, mw1n;
#pragma unroll
    for (int i = 0; i < 4; ++i) {
        const int c = tid + i * 256;
        kv[i] = *(const short8*)(Kb + (size_t)(c >> 3) * DKH + (c & 7) * 8);
    }
#pragma unroll
    for (int i = 0; i < 4; ++i) {
        const int c = tid + i * 256;
        vv[i] = *(const short8*)(Vb + (size_t)(c >> 4) * NSEQ + (c & 15) * 8);
    }
    mw0n = Mv0[0];
    mw1n = Mv1[0];

    for (int kt = 0; kt < NSEQ / 128; ++kt) {
        ushort_t* Ksb = Ks[kt & 1];
        ushort_t* Vsb = Vs[kt & 1];

        // ---- write staged regs into this tile's buffers ----
#pragma unroll
        for (int i = 0; i < 4; ++i) {
            const int c = tid + i * 256;
            *(short8*)&Ksb[(c >> 3) * 72 + (c & 7) * 8] = kv[i];
        }
#pragma unroll
        for (int i = 0; i < 4; ++i) {
            const int c = tid + i * 256;
            *(short8*)&Vsb[(c >> 4) * 136 + (c & 15) * 8] = vv[i];
        }
        const uint4 mw0 = mw0n;
        const uint4 mw1 = mw1n;

        __syncthreads();   // single barrier: buf[kt&1] staged by all waves

        // ---- issue next tile's gather (latency hides under compute below) ----
        if (kt + 1 < NSEQ / 128) {
            const int kn = (kt + 1) * 128;
#pragma unroll
            for (int i = 0; i < 4; ++i) {
                const int c = tid + i * 256;
                kv[i] = *(const short8*)(Kb + (size_t)(kn + (c >> 3)) * DKH + (c & 7) * 8);
            }
#pragma unroll
            for (int i = 0; i < 4; ++i) {
                const int c = tid + i * 256;
                vv[i] = *(const short8*)(Vb + (size_t)(c >> 4) * NSEQ + kn + (c & 15) * 8);
            }
            mw0n = Mv0[kt + 1];
            mw1n = Mv1[kt + 1];
        }

        const unsigned int wsh0[4] = {mw0.x >> (quad * 4), mw0.y >> (quad * 4),
                                      mw0.z >> (quad * 4), mw0.w >> (quad * 4)};
        const unsigned int wsh1[4] = {mw1.x >> (quad * 4), mw1.y >> (quad * 4),
                                      mw1.z >> (quad * 4), mw1.w >> (quad * 4)};

        // ---- fused per-kf: S (2 frags) -> softmax -> permlane transpose -> l + PV ----
#pragma unroll
        for (int kf = 0; kf < 4; ++kf) {
            unsigned xe0, ye0, xo0, yo0;   // group 0: fr even / odd packed words
            unsigned xe1, ye1, xo1, yo1;   // group 1
            SFRAG(kf * 2,     xe0, ye0, xe1, ye1);
            SFRAG(kf * 2 + 1, xo0, yo0, xo1, yo1);

            permlane32_swap(xe0, xo0); permlane32_swap(ye0, yo0);
            permlane16_swap(xe0, xo0); permlane16_swap(ye0, yo0);
            permlane32_swap(xe1, xo1); permlane32_swap(ye1, yo1);
            permlane16_swap(xe1, xo1); permlane16_swap(ye1, yo1);

            const uint4 u0 = {xe0, ye0, xo0, yo0};
            const uint4 u1 = {xe1, ye1, xo1, yo1};
            const short8 pf0 = __builtin_bit_cast(short8, u0);
            const short8 pf1 = __builtin_bit_cast(short8, u1);

            // l += P.1 and O += P.V on the MFMA pipe (priority-boosted cluster)
            __builtin_amdgcn_s_setprio(1);
            accL0 = mfma_bf16(pf0, ones, accL0);
            accL1 = mfma_bf16(pf1, ones, accL1);
#pragma unroll
            for (int ct = 0; ct < 4; ++ct) {
                const short8 vb =
                    *(const short8*)&Vsb[(ct * 16 + l16) * 136 + kf * 32 + quad * 8];
                accA[ct] = mfma_bf16(pf0, vb, accA[ct]);
                accB[ct] = mfma_bf16(pf1, vb, accB[ct]);
            }
            __builtin_amdgcn_s_setprio(0);
        }
    }
#undef SFRAG

    // ---- epilogue: l is in accL at exactly (q = qw + quad*4 + r); no shuffles ----
#pragma unroll
    for (int r = 0; r < 4; ++r) {
        const int q0 = qw + quad * 4 + r;
        const int q1 = q0 + 16;
        const float sc0 = kmas[b * NSEQ + q0] / accL0[r];
        const float sc1 = kmas[b * NSEQ + q1] / accL1[r];
#pragma unroll
        for (int ct = 0; ct < 4; ++ct) {
            y[(size_t)(b * NSEQ + q0) * DMODEL + h * DKH + ct * 16 + l16] =
                f2bf(accA[ct][r] * sc0);
            y[(size_t)(b * NSEQ + q1) * DMODEL + h * DKH + ct * 16 + l16] =
                f2bf(accB[ct][r] * sc1);
        }
    }
}

extern "C" void kernel_launch(void* const* d_in, const int* in_sizes, int n_in,
                              void* d_out, int out_size, void* d_ws, size_t ws_size,
                              hipStream_t stream) {
    (void)in_sizes; (void)n_in; (void)out_size; (void)ws_size;
    const float* Q  = (const float*)d_in[0];
    const float* K  = (const float*)d_in[1];
    const float* V  = (const float*)d_in[2];
    const float* qm = (const float*)d_in[3];
    const float* km = (const float*)d_in[4];
    const float* am = (const float*)d_in[5];
    const float* WQ = (const float*)d_in[6];
    const float* WK = (const float*)d_in[7];
    const float* WV = (const float*)d_in[8];
    const float* WO = (const float*)d_in[9];

    const size_t XN = (size_t)MROWS * DMODEL;        // 4,194,304
    const size_t WN = (size_t)DMODEL * DMODEL;       // 262,144
    ushort_t* Xbf = (ushort_t*)d_ws;                 // Q,K,V bf16: 3*XN
    ushort_t* Wbf = Xbf + 3 * XN;                    // WQ,WK,WV,WO bf16: 4*WN
    ushort_t* WOb = Wbf + 3 * WN;
    ushort_t* Qh  = Wbf + 4 * WN;
    ushort_t* Kh  = Qh + XN;
    ushort_t* Vt  = Kh + XN;
    ushort_t* y   = Vt + XN;
    // packed mask lives in d_out (2 MB of 16 MB); gemm_out fully overwrites d_out afterwards
    unsigned int* Mbits = (unsigned int*)d_out;
    float* out = (float*)d_out;

    hipLaunchKernelGGL(cvt_all, dim3(4096, 8), dim3(256), 0, stream,
                       Q, K, V, WQ, WK, WV, WO, am, Xbf, Wbf, Mbits, (int)(XN / 4));

    hipLaunchKernelGGL(gemm_proj, dim3(MROWS / 64, DMODEL / 64, 3), dim3(256), 0, stream,
                       Xbf, Wbf, qm, km, Qh, Kh, Vt);

    hipLaunchKernelGGL(attn_kernel, dim3(512), dim3(256), 0, stream,
                       Qh, Kh, Vt, Mbits, km, y);

    hipLaunchKernelGGL(gemm_out, dim3(MROWS / 64, DMODEL / 64), dim3(256), 0, stream,
                       y, WOb, km, out);
}

// Round 17
// 237.889 us; speedup vs baseline: 1.0232x; 1.0232x over previous
//
#include <hip/hip_runtime.h>

// MultiHeadAttention: BS=4, N=2048, D=512, H=8, DK=64. fp32 in/out, bf16 MFMA compute.
// Round 22: R16 lesson: attn is issue-bound (XCD swizzle cut FETCH 3.4x, zero time
// gain; setprio neutral) -> attn reverted to exact R15 (61us best). New target:
// gemm_proj's epilogue wrote Qh/Kh as 16 scalar 2B stores/thread (32B-useful/line)
// and Vt as lane-scattered 4KB-strided ushort4 (64 lines/instr). Now staged through
// LDS (reuses As/Bs, stride-72 pad) and written fully coalesced (128B rows).
// GEMM K-loops (R11 64x64), gemm_out, cvt_all frozen.

#define BS_    4
#define NSEQ   2048
#define DMODEL 512
#define NH     8
#define DKH    64
#define MROWS  (BS_ * NSEQ)   // 8192
#define NW32   (NSEQ / 32)    // 64 mask words per row
#define NWORDS (BS_ * NSEQ * NSEQ / 32)  // 524288 packed mask words

typedef unsigned short ushort_t;
typedef __attribute__((ext_vector_type(8))) short short8;   // 8 bf16 (4 VGPRs)
typedef __attribute__((ext_vector_type(4))) float floatx4;  // 4 fp32 acc

__device__ __forceinline__ ushort_t f2bf(float f) {
    unsigned int x = __builtin_bit_cast(unsigned int, f);
    unsigned int lsb = (x >> 16) & 1u;
    x += 0x7fffu + lsb;          // round-to-nearest-even
    return (ushort_t)(x >> 16);
}
__device__ __forceinline__ floatx4 mfma_bf16(short8 a, short8 b, floatx4 c) {
    return __builtin_amdgcn_mfma_f32_16x16x32_bf16(a, b, c, 0, 0, 0);
}
__device__ __forceinline__ void gld16(const ushort_t* g, ushort_t* l) {
    __builtin_amdgcn_global_load_lds(
        (const __attribute__((address_space(1))) unsigned int*)g,
        (__attribute__((address_space(3))) unsigned int*)l, 16, 0, 0);
}
__device__ __forceinline__ unsigned int cvt_pk_bf16(float lo, float hi) {
    unsigned int r;
    asm("v_cvt_pk_bf16_f32 %0, %1, %2" : "=v"(r) : "v"(lo), "v"(hi));
    return r;
}
__device__ __forceinline__ float fexp2(float x) {
#if __has_builtin(__builtin_amdgcn_exp2f)
    return __builtin_amdgcn_exp2f(x);   // raw v_exp_f32
#else
    return exp2f(x);
#endif
}
// gfx950: swap a[32:63] <-> b[0:31]
__device__ __forceinline__ void permlane32_swap(unsigned& a, unsigned& b) {
    asm volatile("v_permlane32_swap_b32 %0, %1" : "+v"(a), "+v"(b));
}
// gfx950: swap a[16:31]<->b[0:15] and a[48:63]<->b[32:47]
__device__ __forceinline__ void permlane16_swap(unsigned& a, unsigned& b) {
    asm volatile("v_permlane16_swap_b32 %0, %1" : "+v"(a), "+v"(b));
}
// spread 8 bits of b to positions 0,4,8,...,28
__device__ __forceinline__ unsigned spread4(unsigned b) {
    b = (b | (b << 12)) & 0x000F000Fu;
    b = (b | (b << 6))  & 0x03030303u;
    b = (b | (b << 3))  & 0x11111111u;
    return b;
}

// ---------------- fp32 -> bf16 converts + weights + att_mas bit-pack ----------------
// grid (4096, 8): y=0..2 QKV slices; y=3 weights; y=4..7 mask quarters (coalesced
// float4/thread + 4 ballots; lanes 0..7 of each wave emit the 8 packed words).
__global__ __launch_bounds__(256) void cvt_all(const float* __restrict__ a,
                                               const float* __restrict__ b,
                                               const float* __restrict__ c,
                                               const float* __restrict__ wq,
                                               const float* __restrict__ wk,
                                               const float* __restrict__ wv,
                                               const float* __restrict__ wo,
                                               const float* __restrict__ am,
                                               ushort_t* __restrict__ dst,
                                               ushort_t* __restrict__ wdst,
                                               unsigned int* __restrict__ mb, int n4) {
    const int i = blockIdx.x * blockDim.x + threadIdx.x;
    const int yy = blockIdx.y;
    if (yy >= 4) {
        // g indexes float4s of att_mas; elements 4g..4g+3; word w = elems 32w..32w+31
        const int g = ((yy - 4) * 4096 + blockIdx.x) * 256 + threadIdx.x;
        const float4 v = ((const float4*)am)[g];
        const unsigned long long b0 = __ballot(v.x != 0.f);
        const unsigned long long b1 = __ballot(v.y != 0.f);
        const unsigned long long b2 = __ballot(v.z != 0.f);
        const unsigned long long b3 = __ballot(v.w != 0.f);
        const int l = threadIdx.x & 63;
        if (l < 8) {
            const unsigned B0 = (unsigned)((b0 >> (8 * l)) & 0xFFull);
            const unsigned B1 = (unsigned)((b1 >> (8 * l)) & 0xFFull);
            const unsigned B2 = (unsigned)((b2 >> (8 * l)) & 0xFFull);
            const unsigned B3 = (unsigned)((b3 >> (8 * l)) & 0xFFull);
            const unsigned w = spread4(B0) | (spread4(B1) << 1) |
                               (spread4(B2) << 2) | (spread4(B3) << 3);
            const int g0 = g & ~63;           // wave-base float4 index
            mb[(g0 >> 3) + l] = w;
        }
        return;
    }
    if (yy == 3) {
        const int wn4 = DMODEL * DMODEL / 4;          // 65536 float4 per weight
        if (i < 4 * wn4) {
            const int w = i >> 16;
            const float* src = (w == 0) ? wq : (w == 1) ? wk : (w == 2) ? wv : wo;
            const float4 v = ((const float4*)src)[i & (wn4 - 1)];
            ushort4 o;
            o.x = f2bf(v.x); o.y = f2bf(v.y); o.z = f2bf(v.z); o.w = f2bf(v.w);
            ((ushort4*)wdst)[i] = o;
        }
        return;
    }
    const float* src = (yy == 0) ? a : (yy == 1) ? b : c;
    ushort_t* d = dst + (size_t)yy * ((size_t)n4 * 4);
    const float4 v = ((const float4*)src)[i];
    ushort4 o;
    o.x = f2bf(v.x); o.y = f2bf(v.y); o.z = f2bf(v.z); o.w = f2bf(v.w);
    ((ushort4*)d)[i] = o;
}

// ---------------- fused projection GEMM (Q/K/V via blockIdx.z), 64x64 tile, BK=64 ----------------
// K-loop = R11 version. Epilogue: output tile staged through LDS (smem reuse) and
// written coalesced: Qh/Kh 128B-contiguous rows along cc; Vt stored transposed in
// LDS (Tv[cc][n], packed uint2) and written 128B-contiguous along n.
__global__ __launch_bounds__(256) void gemm_proj(const ushort_t* __restrict__ Xall,
                                                 const ushort_t* __restrict__ Wall,
                                                 const float* __restrict__ qmas,
                                                 const float* __restrict__ kmas,
                                                 ushort_t* __restrict__ Qh,
                                                 ushort_t* __restrict__ Kh,
                                                 ushort_t* __restrict__ Vt) {
    __shared__ __align__(16) ushort_t smem[2 * 64 * 64];   // 16 KB: As | Bs, reused by epilogue
    ushort_t* As = smem;
    ushort_t* Bs = smem + 64 * 64;
    const int z = blockIdx.z;
    const ushort_t* X  = Xall + (size_t)z * MROWS * DMODEL;
    const ushort_t* Wb = Wall + (size_t)z * DMODEL * DMODEL;
    const float* rowmask = (z == 0) ? qmas : kmas;

    const int tid  = threadIdx.x;
    const int wave = tid >> 6;
    const int lane = tid & 63;
    const int l16  = lane & 15;
    const int quad = lane >> 4;
    const int wr   = wave >> 1;
    const int wc   = wave & 1;
    const int m0   = blockIdx.x * 64;
    const int n0   = blockIdx.y * 64;

    floatx4 acc[2][2];
#pragma unroll
    for (int t = 0; t < 2; ++t)
#pragma unroll
        for (int u = 0; u < 2; ++u) acc[t][u] = (floatx4){0.f, 0.f, 0.f, 0.f};

    for (int k0 = 0; k0 < DMODEL; k0 += 64) {
#pragma unroll
        for (int i = 0; i < 2; ++i) {
            const int cch = tid + i * 256;               // 16B chunk id, 0..511
            const int row = cch >> 3;
            const int sc  = 8 * ((cch & 7) ^ (row & 7)); // pre-swizzled source col
            gld16(X  + (size_t)(m0 + row) * DMODEL + k0 + sc, &As[cch * 8]);
            gld16(Wb + (size_t)(n0 + row) * DMODEL + k0 + sc, &Bs[cch * 8]);
        }
        __syncthreads();
#pragma unroll
        for (int kk = 0; kk < 64; kk += 32) {
            const int pc = (((kk >> 3) | quad) ^ (l16 & 7)) * 8;
            short8 a[2], b[2];
#pragma unroll
            for (int t = 0; t < 2; ++t)
                a[t] = *(const short8*)&As[(wr * 32 + t * 16 + l16) * 64 + pc];
#pragma unroll
            for (int u = 0; u < 2; ++u)
                b[u] = *(const short8*)&Bs[(wc * 32 + u * 16 + l16) * 64 + pc];
#pragma unroll
            for (int t = 0; t < 2; ++t)
#pragma unroll
                for (int u = 0; u < 2; ++u) acc[t][u] = mfma_bf16(a[t], b[u], acc[t][u]);
        }
        __syncthreads();   // also protects smem reuse by the epilogue below
    }

    float rm[2][4];
#pragma unroll
    for (int t = 0; t < 2; ++t)
#pragma unroll
        for (int r = 0; r < 4; ++r)
            rm[t][r] = rowmask[m0 + wr * 32 + t * 16 + quad * 4 + r];
    if (z == 0) {
        // fold log2(e)/sqrt(dk) into Qh so attn uses exp2(S) directly
#pragma unroll
        for (int t = 0; t < 2; ++t)
#pragma unroll
            for (int r = 0; r < 4; ++r) rm[t][r] *= 0.18033688011112042f;
    }

    const int bb = m0 >> 11;          // batch
    const int h  = blockIdx.y;        // 64-col slab == one head
    const int nb = m0 & (NSEQ - 1);   // sequence base of this tile
    ushort_t* T = smem;               // epilogue tile, stride 72 (9216 B <= 16 KB)

    if (z < 2) {
        // ---- Tq[row=m_rel][col=cc] ----
#pragma unroll
        for (int t = 0; t < 2; ++t)
#pragma unroll
            for (int u = 0; u < 2; ++u) {
                const int col = wc * 32 + u * 16 + l16;
#pragma unroll
                for (int r = 0; r < 4; ++r) {
                    const int row = wr * 32 + t * 16 + quad * 4 + r;
                    T[row * 72 + col] = f2bf(acc[t][u][r] * rm[t][r]);
                }
            }
        __syncthreads();
        ushort_t* dst = (z == 0) ? Qh : Kh;
        const size_t base = ((size_t)(bb * NH + h) * NSEQ + nb) * DKH;
#pragma unroll
        for (int p = 0; p < 2; ++p) {
            const int row = (tid >> 3) + p * 32;
            const int ch  = tid & 7;
            const short8 v = *(const short8*)&T[row * 72 + ch * 8];
            *(short8*)&dst[base + (size_t)row * DKH + ch * 8] = v;
        }
    } else {
        // ---- Tv[row=cc][col=n_rel] (transposed), packed uint2 fills ----
#pragma unroll
        for (int t = 0; t < 2; ++t)
#pragma unroll
            for (int u = 0; u < 2; ++u) {
                const int cc = wc * 32 + u * 16 + l16;
                const int nr = wr * 32 + t * 16 + quad * 4;
                uint2 pk;
                pk.x = cvt_pk_bf16(acc[t][u][0] * rm[t][0], acc[t][u][1] * rm[t][1]);
                pk.y = cvt_pk_bf16(acc[t][u][2] * rm[t][2], acc[t][u][3] * rm[t][3]);
                *(uint2*)&T[cc * 72 + nr] = pk;
            }
        __syncthreads();
        const size_t base = ((size_t)(bb * NH + h) * DKH) * NSEQ + nb;
#pragma unroll
        for (int p = 0; p < 2; ++p) {
            const int cc = (tid >> 3) + p * 32;
            const int ch = tid & 7;
            const short8 v = *(const short8*)&T[cc * 72 + ch * 8];
            *(short8*)&Vt[base + (size_t)cc * NSEQ + ch * 8] = v;
        }
    }
}

// ---------------- output GEMM, 64x64 tile, BK=64, swizzled (R11 version) ----------------
__global__ __launch_bounds__(256) void gemm_out(const ushort_t* __restrict__ X,
                                                const ushort_t* __restrict__ Wb,
                                                const float* __restrict__ rowmask,
                                                float* __restrict__ dst) {
    __shared__ ushort_t As[64 * 64];
    __shared__ ushort_t Bs[64 * 64];
    const int tid  = threadIdx.x;
    const int wave = tid >> 6;
    const int lane = tid & 63;
    const int l16  = lane & 15;
    const int quad = lane >> 4;
    const int wr   = wave >> 1;
    const int wc   = wave & 1;
    const int m0   = blockIdx.x * 64;
    const int n0   = blockIdx.y * 64;

    floatx4 acc[2][2];
#pragma unroll
    for (int t = 0; t < 2; ++t)
#pragma unroll
        for (int u = 0; u < 2; ++u) acc[t][u] = (floatx4){0.f, 0.f, 0.f, 0.f};

    for (int k0 = 0; k0 < DMODEL; k0 += 64) {
#pragma unroll
        for (int i = 0; i < 2; ++i) {
            const int cch = tid + i * 256;
            const int row = cch >> 3;
            const int sc  = 8 * ((cch & 7) ^ (row & 7));
            gld16(X  + (size_t)(m0 + row) * DMODEL + k0 + sc, &As[cch * 8]);
            gld16(Wb + (size_t)(n0 + row) * DMODEL + k0 + sc, &Bs[cch * 8]);
        }
        __syncthreads();
#pragma unroll
        for (int kk = 0; kk < 64; kk += 32) {
            const int pc = (((kk >> 3) | quad) ^ (l16 & 7)) * 8;
            short8 a[2], b[2];
#pragma unroll
            for (int t = 0; t < 2; ++t)
                a[t] = *(const short8*)&As[(wr * 32 + t * 16 + l16) * 64 + pc];
#pragma unroll
            for (int u = 0; u < 2; ++u)
                b[u] = *(const short8*)&Bs[(wc * 32 + u * 16 + l16) * 64 + pc];
#pragma unroll
            for (int t = 0; t < 2; ++t)
#pragma unroll
                for (int u = 0; u < 2; ++u) acc[t][u] = mfma_bf16(a[t], b[u], acc[t][u]);
        }
        __syncthreads();
    }

#pragma unroll
    for (int t = 0; t < 2; ++t) {
#pragma unroll
        for (int r = 0; r < 4; ++r) {
            const int m = m0 + wr * 32 + t * 16 + quad * 4 + r;
            const float rm = rowmask[m];
#pragma unroll
            for (int u = 0; u < 2; ++u) {
                const int d = n0 + wc * 32 + u * 16 + l16;
                dst[(size_t)m * DMODEL + d] = acc[t][u][r] * rm;
            }
        }
    }
}

// ---------------- flash attention: 128-q blocks, 2 q-groups/wave, dbuf LDS, 1 barrier/tile ----------------
// Exact R15 version (best measured: 61.0us). K+V dbuf, next-tile gather issued
// after the single barrier, in-register P via permlane, l via mfma(P, ones).
__global__ __launch_bounds__(256, 2) void attn_kernel(const ushort_t* __restrict__ Qh,
                                                      const ushort_t* __restrict__ Kh,
                                                      const ushort_t* __restrict__ Vt,
                                                      const unsigned int* __restrict__ Mb,
                                                      const float* __restrict__ kmas,
                                                      ushort_t* __restrict__ y) {
    __shared__ __align__(16) ushort_t Ks[2][128 * 72];   // 36864 B
    __shared__ __align__(16) ushort_t Vs[2][64 * 136];   // 34816 B (total 71680)

    const int tid  = threadIdx.x;
    const int lane = tid & 63;
    const int wave = tid >> 6;
    const int l16  = lane & 15;
    const int quad = lane >> 4;
    const int h    = blockIdx.y;
    const int b    = blockIdx.z;
    const int qw   = blockIdx.x * 128 + wave * 32;   // this wave's 32 q-rows

    const ushort_t* Kb = Kh + (size_t)(b * NH + h) * NSEQ * DKH;
    const ushort_t* Vb = Vt + (size_t)(b * NH + h) * DKH * NSEQ;
    // per-lane mask rows: q = qw + l16 (group 0) and qw + 16 + l16 (group 1)
    const uint4* Mv0 = (const uint4*)(Mb + ((size_t)(b * NSEQ + qw) + l16) * NW32);
    const uint4* Mv1 = (const uint4*)(Mb + ((size_t)(b * NSEQ + qw) + 16 + l16) * NW32);

    const ushort_t* Qp0 = Qh + ((size_t)((b * NH + h) * NSEQ) + qw + l16) * DKH + quad * 8;
    const ushort_t* Qp1 = Qp0 + 16 * DKH;
    const short8 qf0a = *(const short8*)Qp0;
    const short8 qf0b = *(const short8*)(Qp0 + 32);
    const short8 qf1a = *(const short8*)Qp1;
    const short8 qf1b = *(const short8*)(Qp1 + 32);

    // all-ones bf16 B-operand for row-sum MFMA (bf16 1.0 = 0x3F80)
    const short8 ones = {(short)0x3F80, (short)0x3F80, (short)0x3F80, (short)0x3F80,
                         (short)0x3F80, (short)0x3F80, (short)0x3F80, (short)0x3F80};

    floatx4 accA[4], accB[4];
    floatx4 accL0 = (floatx4){0.f, 0.f, 0.f, 0.f};   // row-sums l, group 0
    floatx4 accL1 = (floatx4){0.f, 0.f, 0.f, 0.f};   // row-sums l, group 1
#pragma unroll
    for (int ct = 0; ct < 4; ++ct) {
        accA[ct] = (floatx4){0.f, 0.f, 0.f, 0.f};
        accB[ct] = (floatx4){0.f, 0.f, 0.f, 0.f};
    }

// S fragment FR (compile-time after unroll) -> packed P words for both groups
#define SFRAG(FR, PX0, PY0, PX1, PY1) do {                                          \
    const short8 ka = *(const short8*)&Ksb[((FR) * 16 + l16) * 72 + quad * 8];      \
    const short8 kb = *(const short8*)&Ksb[((FR) * 16 + l16) * 72 + 32 + quad * 8]; \
    floatx4 s0 = {0.f, 0.f, 0.f, 0.f};                                              \
    s0 = mfma_bf16(ka, qf0a, s0);                                                   \
    s0 = mfma_bf16(kb, qf0b, s0);                                                   \
    floatx4 s1 = {0.f, 0.f, 0.f, 0.f};                                              \
    s1 = mfma_bf16(ka, qf1a, s1);                                                   \
    s1 = mfma_bf16(kb, qf1b, s1);                                                   \
    float p0[4], p1[4];                                                             \
    _Pragma("unroll")                                                               \
    for (int r = 0; r < 4; ++r) {                                                   \
        const int bitp = (((FR) & 1) << 4) + r;                                     \
        const unsigned m0m =                                                        \
            (unsigned)__builtin_amdgcn_sbfe((int)wsh0[(FR) >> 1], bitp, 1);         \
        const unsigned m1m =                                                        \
            (unsigned)__builtin_amdgcn_sbfe((int)wsh1[(FR) >> 1], bitp, 1);         \
        p0[r] = __builtin_bit_cast(float,                                           \
                    __builtin_bit_cast(unsigned, fexp2(s0[r])) & m0m);              \
        p1[r] = __builtin_bit_cast(float,                                           \
                    __builtin_bit_cast(unsigned, fexp2(s1[r])) & m1m);              \
    }                                                                               \
    PX0 = cvt_pk_bf16(p0[0], p0[1]); PY0 = cvt_pk_bf16(p0[2], p0[3]);               \
    PX1 = cvt_pk_bf16(p1[0], p1[1]); PY1 = cvt_pk_bf16(p1[2], p1[3]);               \
} while (0)

    // ---- prologue: gather tile 0 ----
    short8 kv[4], vv[4];
    uint4 mw0n, mw1n;
#pragma unroll
    for (int i = 0; i < 4; ++i) {
        const int c = tid + i * 256;
        kv[i] = *(const short8*)(Kb + (size_t)(c >> 3) * DKH + (c & 7) * 8);
    }
#pragma unroll
    for (int i = 0; i < 4; ++i) {
        const int c = tid + i * 256;
        vv[i] = *(const short8*)(Vb + (size_t)(c >> 4) * NSEQ + (c & 15) * 8);
    }
    mw0n = Mv0[0];
    mw1n = Mv1[0];

    for (int kt = 0; kt < NSEQ / 128; ++kt) {
        ushort_t* Ksb = Ks[kt & 1];
        ushort_t* Vsb = Vs[kt & 1];

        // ---- write staged regs into this tile's buffers ----
#pragma unroll
        for (int i = 0; i < 4; ++i) {
            const int c = tid + i * 256;
            *(short8*)&Ksb[(c >> 3) * 72 + (c & 7) * 8] = kv[i];
        }
#pragma unroll
        for (int i = 0; i < 4; ++i) {
            const int c = tid + i * 256;
            *(short8*)&Vsb[(c >> 4) * 136 + (c & 15) * 8] = vv[i];
        }
        const uint4 mw0 = mw0n;
        const uint4 mw1 = mw1n;

        __syncthreads();   // single barrier: buf[kt&1] staged by all waves

        // ---- issue next tile's gather (latency hides under compute below) ----
        if (kt + 1 < NSEQ / 128) {
            const int kn = (kt + 1) * 128;
#pragma unroll
            for (int i = 0; i < 4; ++i) {
                const int c = tid + i * 256;
                kv[i] = *(const short8*)(Kb + (size_t)(kn + (c >> 3)) * DKH + (c & 7) * 8);
            }
#pragma unroll
            for (int i = 0; i < 4; ++i) {
                const int c = tid + i * 256;
                vv[i] = *(const short8*)(Vb + (size_t)(c >> 4) * NSEQ + kn + (c & 15) * 8);
            }
            mw0n = Mv0[kt + 1];
            mw1n = Mv1[kt + 1];
        }

        const unsigned int wsh0[4] = {mw0.x >> (quad * 4), mw0.y >> (quad * 4),
                                      mw0.z >> (quad * 4), mw0.w >> (quad * 4)};
        const unsigned int wsh1[4] = {mw1.x >> (quad * 4), mw1.y >> (quad * 4),
                                      mw1.z >> (quad * 4), mw1.w >> (quad * 4)};

        // ---- fused per-kf: S (2 frags) -> softmax -> permlane transpose -> l + PV ----
#pragma unroll
        for (int kf = 0; kf < 4; ++kf) {
            unsigned xe0, ye0, xo0, yo0;   // group 0: fr even / odd packed words
            unsigned xe1, ye1, xo1, yo1;   // group 1
            SFRAG(kf * 2,     xe0, ye0, xe1, ye1);
            SFRAG(kf * 2 + 1, xo0, yo0, xo1, yo1);

            permlane32_swap(xe0, xo0); permlane32_swap(ye0, yo0);
            permlane16_swap(xe0, xo0); permlane16_swap(ye0, yo0);
            permlane32_swap(xe1, xo1); permlane32_swap(ye1, yo1);
            permlane16_swap(xe1, xo1); permlane16_swap(ye1, yo1);

            const uint4 u0 = {xe0, ye0, xo0, yo0};
            const uint4 u1 = {xe1, ye1, xo1, yo1};
            const short8 pf0 = __builtin_bit_cast(short8, u0);
            const short8 pf1 = __builtin_bit_cast(short8, u1);

            // l += P.1 on the MFMA pipe
            accL0 = mfma_bf16(pf0, ones, accL0);
            accL1 = mfma_bf16(pf1, ones, accL1);

            // O += P.V : each V fragment read once -> both q-groups
#pragma unroll
            for (int ct = 0; ct < 4; ++ct) {
                const short8 vb =
                    *(const short8*)&Vsb[(ct * 16 + l16) * 136 + kf * 32 + quad * 8];
                accA[ct] = mfma_bf16(pf0, vb, accA[ct]);
                accB[ct] = mfma_bf16(pf1, vb, accB[ct]);
            }
        }
    }
#undef SFRAG

    // ---- epilogue: l is in accL at exactly (q = qw + quad*4 + r); no shuffles ----
#pragma unroll
    for (int r = 0; r < 4; ++r) {
        const int q0 = qw + quad * 4 + r;
        const int q1 = q0 + 16;
        const float sc0 = kmas[b * NSEQ + q0] / accL0[r];
        const float sc1 = kmas[b * NSEQ + q1] / accL1[r];
#pragma unroll
        for (int ct = 0; ct < 4; ++ct) {
            y[(size_t)(b * NSEQ + q0) * DMODEL + h * DKH + ct * 16 + l16] =
                f2bf(accA[ct][r] * sc0);
            y[(size_t)(b * NSEQ + q1) * DMODEL + h * DKH + ct * 16 + l16] =
                f2bf(accB[ct][r] * sc1);
        }
    }
}

extern "C" void kernel_launch(void* const* d_in, const int* in_sizes, int n_in,
                              void* d_out, int out_size, void* d_ws, size_t ws_size,
                              hipStream_t stream) {
    (void)in_sizes; (void)n_in; (void)out_size; (void)ws_size;
    const float* Q  = (const float*)d_in[0];
    const float* K  = (const float*)d_in[1];
    const float* V  = (const float*)d_in[2];
    const float* qm = (const float*)d_in[3];
    const float* km = (const float*)d_in[4];
    const float* am = (const float*)d_in[5];
    const float* WQ = (const float*)d_in[6];
    const float* WK = (const float*)d_in[7];
    const float* WV = (const float*)d_in[8];
    const float* WO = (const float*)d_in[9];

    const size_t XN = (size_t)MROWS * DMODEL;        // 4,194,304
    const size_t WN = (size_t)DMODEL * DMODEL;       // 262,144
    ushort_t* Xbf = (ushort_t*)d_ws;                 // Q,K,V bf16: 3*XN
    ushort_t* Wbf = Xbf + 3 * XN;                    // WQ,WK,WV,WO bf16: 4*WN
    ushort_t* WOb = Wbf + 3 * WN;
    ushort_t* Qh  = Wbf + 4 * WN;
    ushort_t* Kh  = Qh + XN;
    ushort_t* Vt  = Kh + XN;
    ushort_t* y   = Vt + XN;
    // packed mask lives in d_out (2 MB of 16 MB); gemm_out fully overwrites d_out afterwards
    unsigned int* Mbits = (unsigned int*)d_out;
    float* out = (float*)d_out;

    hipLaunchKernelGGL(cvt_all, dim3(4096, 8), dim3(256), 0, stream,
                       Q, K, V, WQ, WK, WV, WO, am, Xbf, Wbf, Mbits, (int)(XN / 4));

    hipLaunchKernelGGL(gemm_proj, dim3(MROWS / 64, DMODEL / 64, 3), dim3(256), 0, stream,
                       Xbf, Wbf, qm, km, Qh, Kh, Vt);

    hipLaunchKernelGGL(attn_kernel, dim3(NSEQ / 128, NH, BS_), dim3(256), 0, stream,
                       Qh, Kh, Vt, Mbits, km, y);

    hipLaunchKernelGGL(gemm_out, dim3(MROWS / 64, DMODEL / 64), dim3(256), 0, stream,
                       y, WOb, km, out);
}